// Round 7
// baseline (5329.313 us; speedup 1.0000x reference)
//
#include <hip/hip_runtime.h>

typedef __attribute__((ext_vector_type(8))) short short8;
typedef __attribute__((ext_vector_type(4))) float floatx4;
typedef __attribute__((ext_vector_type(16))) float floatx16;
typedef unsigned int uint;
typedef unsigned short ushort;
typedef unsigned long long ull;
typedef __attribute__((ext_vector_type(4))) uint uintx4;
typedef __attribute__((ext_vector_type(4))) int intx4;

#define B_ 512
#define S_ 200
#define H_ 512
#define VOCAB_ 2002

__device__ __forceinline__ ushort f2bfbits(float f) {
  union { float f; uint u; } c; c.f = f;
  uint u = c.u;
  u += 0x7fffu + ((u >> 16) & 1u);   // RNE
  return (ushort)(u >> 16);
}
__device__ __forceinline__ float bf2f_(ushort u) {
  union { uint i; float f; } c; c.i = ((uint)u) << 16; return c.f;
}
__device__ __forceinline__ float sigmoidf_(float x) { return 1.f / (1.f + __expf(-x)); }
__device__ __forceinline__ float tanhf_(float x) { return 2.f / (1.f + __expf(-2.f * x)) - 1.f; }
__device__ __forceinline__ float clamp30(float x) { return fminf(fmaxf(x, -30.f), 30.f); }

// split f32[8] -> (hi, lo) bf16 short8 pair; hi+lo carries ~16 mantissa bits
__device__ __forceinline__ void split8(const float* p, short8& hi, short8& lo) {
#pragma unroll
  for (int j = 0; j < 8; ++j) {
    const float f = p[j];
    const ushort h = f2bfbits(f);
    hi[j] = (short)h;
    lo[j] = (short)f2bfbits(f - bf2f_(h));
  }
}

// --- L2-cached, L1-bypassing 16B load (staging; fresh by prior buffer_inv) ---
__device__ __forceinline__ void ld16_l2(const void* p, uintx4& a) {
  asm volatile("global_load_dwordx4 %0, %1, off sc0"
               : "=&v"(a)
               : "v"(p));
}
// --- MALL-coherent 4B load with embedded drain (spin poll; never cached) ---
__device__ __forceinline__ int ld4_cc_wait(const int* p) {
  int v;
  asm volatile("global_load_dword %0, %1, off sc0 sc1\n\t"
               "s_waitcnt vmcnt(0)"
               : "=v"(v)
               : "v"(p)
               : "memory");
  return v;
}
__device__ __forceinline__ void vm_wait0() {
  asm volatile("s_waitcnt vmcnt(0)" ::: "memory");
}
__device__ __forceinline__ void vm_wait4() {
  asm volatile("s_waitcnt vmcnt(4)" ::: "memory");
}
// --- invalidate this XCD's L2 (acquire-fence primitive, gfx940+ family).
// Subsequent same-wave VMEM requests are issued behind it in program order.
__device__ __forceinline__ void l2_inv() {
  asm volatile("buffer_inv sc1" ::: "memory");
}

// ---------------------------------------------------------------------------
// K1: EncGates[v][n] = emb[v]·W_ih[n]  (f32-accurate via 3-product split MFMA)
// grid (32,126) x 256 thr (4 waves, one 16x16 tile each). Biases added later.
// ---------------------------------------------------------------------------
template <typename ET>
__global__ void encg_kernel(const float* __restrict__ emb, const float* __restrict__ Wih,
                            ET* __restrict__ encg) {
  const int w = threadIdx.x >> 6, l = threadIdx.x & 63;
  const int ln = l & 15, lk = l >> 4;
  const int n = (blockIdx.x * 4 + w) * 16 + ln;
  const int m = blockIdx.y * 16 + ln;
  const int mA = (m < VOCAB_) ? m : 0;
  const float* ap = emb + (size_t)mA * 512 + lk * 8;
  const float* bp = Wih + (size_t)n * 512 + lk * 8;
  floatx4 acc = {0.f, 0.f, 0.f, 0.f};
#pragma unroll 4
  for (int kk = 0; kk < 16; ++kk) {
    short8 ah, al, bh, bl;
    split8(ap + kk * 32, ah, al);
    split8(bp + kk * 32, bh, bl);
    acc = __builtin_amdgcn_mfma_f32_16x16x32_bf16(ah, bh, acc, 0, 0, 0);
    acc = __builtin_amdgcn_mfma_f32_16x16x32_bf16(ah, bl, acc, 0, 0, 0);
    acc = __builtin_amdgcn_mfma_f32_16x16x32_bf16(al, bh, acc, 0, 0, 0);
  }
#pragma unroll
  for (int r = 0; r < 4; ++r) {
    const int mo = blockIdx.y * 16 + lk * 4 + r;   // C/D: row=(lane>>4)*4+reg
    if (mo < VOCAB_) {
      if constexpr (sizeof(ET) == 2)
        encg[(size_t)mo * 2048 + n] = (ET)f2bfbits(acc[r]);
      else
        encg[(size_t)mo * 2048 + n] = acc[r];       // col = lane&15
    }
  }
}

// ---------------------------------------------------------------------------
// K2: et[s][b] = sigmoid(P[u].Q[k] + Pb[u] + Qb[k]); f32. grid (200,128)x256.
// ---------------------------------------------------------------------------
__global__ void mf_kernel(const int* __restrict__ us, const int* __restrict__ ss,
                          const float* __restrict__ P, const float* __restrict__ Q,
                          const float* __restrict__ Pb, const float* __restrict__ Qb,
                          float* __restrict__ etb) {
  const int s = blockIdx.x;
  const int w = threadIdx.x >> 6, l = threadIdx.x & 63;
  const int b = blockIdx.y * 4 + w;
  const int u = us[b * S_ + s];
  const int k = ss[b * S_ + s];
  const float4 p0 = *(const float4*)(P + (size_t)u * 512 + l * 8);
  const float4 p1 = *(const float4*)(P + (size_t)u * 512 + l * 8 + 4);
  const float4 q0 = *(const float4*)(Q + (size_t)k * 512 + l * 8);
  const float4 q1 = *(const float4*)(Q + (size_t)k * 512 + l * 8 + 4);
  float dot = p0.x*q0.x + p0.y*q0.y + p0.z*q0.z + p0.w*q0.w
            + p1.x*q1.x + p1.y*q1.y + p1.z*q1.z + p1.w*q1.w;
#pragma unroll
  for (int off = 32; off > 0; off >>= 1) dot += __shfl_xor(dot, off);
  if (l == 0)
    etb[s * B_ + b] = sigmoidf_(dot + Pb[u] + Qb[k]);
}

// ---------------------------------------------------------------------------
// K3: recurrent LSTM, f32-accurate. 256 blocks x 512 thr, 1 block/CU.
// group g=bid&15 owns 32 batch rows; slice ns=bid>>4 owns 32 h-units.
//
// r15 = r14 (passing) with L2-DEDUP of the 16-consumer ht broadcast:
//  - The step time is provably the fetch service time (35MB/step at ~2.9TB/s
//    = 12.7us); 16MB/step of that is 16 blocks/group re-reading the SAME
//    64KB of ht over the uncached path. The ht working set (2MB) fits L2.
//  - New protocol per step: spin on MALL slots (sc0 sc1, unchanged; progress
//    never depends on caching) -> barA -> `buffer_inv sc1` per wave (the
//    gfx940+ agent-acquire primitive: invalidates this XCD's L2; subsequent
//    same-wave VMEM requests issue behind it) -> staging loads with sc0 only
//    (L1-bypass, L2-FILL). First consumer misses to MALL (fresh: producer
//    stores are sc1 write-through, drained pre-publish -- the proven r8
//    ordering); co-XCD consumers then HIT L2 (bid==g mod 16 => bid%8 equal
//    under round-robin => whole group co-XCD). Cross-XCD mapping still
//    correct: inv + MALL refill, just less dedup (G16-safe).
//  - No deadlock ingredient: stores/poll/publish identical to r14.
// ---------------------------------------------------------------------------
template <typename ET>
__global__ __launch_bounds__(512, 2) void lstm_kernel(
    const int* __restrict__ tok, const ET* __restrict__ encg,
    const float* __restrict__ etb, const float* __restrict__ Whh,
    const float* __restrict__ bih, const float* __restrict__ bhh,
    ushort* ht_hi, ushort* ht_lo, int* ctr) {
  __shared__ __align__(16) ushort Ah_lds[32 * 512];   // 32,768 B (XOR-swizzled)
  __shared__ __align__(16) ushort Al_lds[32 * 512];   // 32,768 B
  __shared__ float gp_lds[2 * 128 * 33];              // 33,792 B

  const int bid = blockIdx.x;
  const int g = bid & 15, ns = bid >> 4;
  const int b0 = g * 32, h0 = ns * 32;
  const int tid = threadIdx.x;
  const int w = tid >> 6, l = tid & 63;
  const int nt = w & 3;                 // gate tile (i,f,g,o)
  const int kh = w >> 2;                // K-half (0: cols 0..255, 1: 256..511)

  // slots: group g's 16 producer blocks publish at ctr[g*16 + ns] -- one
  // 64-B line per group, one dword per block.
  int* const myslot = ctr + g * 16 + ns;
  const int* const gslots = ctr + g * 16;

  // --- preload + split this wave's W_hh rows (32 gate cols, its K-half) ---
  // B operand 32x32x16: lane l holds col=l&31, k=(l>>5)*8+j.
  short8 Bh[16], Bl[16];
  {
    const float* wr = Whh + (size_t)(nt * 512 + h0 + (l & 31)) * 512
                    + kh * 256 + (l >> 5) * 8;
#pragma unroll 4
    for (int kk = 0; kk < 16; ++kk)
      split8(wr + kk * 16, Bh[kk], Bl[kk]);
  }

  const int sr = tid >> 4;              // batch row within group (0..31)
  const int sc = tid & 15;              // 16 stagers per row
  const int hh = sc * 2;
  const int bg = b0 + sr;
  float ct0 = 0.f, ct1 = 0.f;

  float bs[4][2];
#pragma unroll
  for (int qq = 0; qq < 4; ++qq) {
    const int col = qq * 512 + h0 + hh;
    bs[qq][0] = bih[col] + bhh[col];
    bs[qq][1] = bih[col + 1] + bhh[col + 1];
  }

  const int swzw = (sr & 7) << 3;       // writer swizzle (ushort units)
  const int swzr = (l & 7) << 3;        // reader swizzle (row = l&31 -> row&7 = l&7)
  const int k8 = (l >> 5) * 8;          // lane's k-offset within 16-wide step
  const int sc8 = sc * 8;               // this thread's base chunk col (ushorts)

  // 48 MFMAs over one K-half; A row = l&31 from swizzled LDS.
  auto mfma_half = [&](int base) -> floatx16 {
    floatx16 a = {0.f,0.f,0.f,0.f,0.f,0.f,0.f,0.f,
                  0.f,0.f,0.f,0.f,0.f,0.f,0.f,0.f};
#pragma unroll
    for (int kk = 0; kk < 16; ++kk) {
      const int ao = (l & 31) * 512 + ((base + kk * 16 + k8) ^ swzr);
      const short8 ah = *(const short8*)(Ah_lds + ao);
      const short8 al = *(const short8*)(Al_lds + ao);
      a = __builtin_amdgcn_mfma_f32_32x32x16_bf16(ah, Bh[kk], a, 0, 0, 0);
      a = __builtin_amdgcn_mfma_f32_32x32x16_bf16(ah, Bl[kk], a, 0, 0, 0);
      a = __builtin_amdgcn_mfma_f32_32x32x16_bf16(al, Bh[kk], a, 0, 0, 0);
    }
    return a;
  };
  // C/D 32x32: col = lane&31, row = (reg&3) + 8*(reg>>2) + 4*(lane>>5)
  auto gp_write = [&](const floatx16& a) {
    float* gpw = gp_lds + kh * 4224 + (nt * 32 + (l & 31)) * 33 + 4 * (l >> 5);
#pragma unroll
    for (int r = 0; r < 16; ++r)
      gpw[(r & 3) + 8 * (r >> 2)] = a[r];
  };

  for (int s = 0; s < S_; ++s) {
    // ---- prefetch nonlinearity inputs (ht-independent; hides under spin) ----
    const int tv = tok[bg * S_ + s];
    float ev = etb[s * B_ + bg];
    float ex[4], ey[4];
#pragma unroll
    for (int qq = 0; qq < 4; ++qq) {
      if constexpr (sizeof(ET) == 2) {
        const uint e2 = *(const uint*)((const ushort*)encg + (size_t)tv * 2048 + qq * 512 + h0 + hh);
        ex[qq] = bf2f_((ushort)(e2 & 0xffffu)); ey[qq] = bf2f_((ushort)(e2 >> 16));
      } else {
        const float2 e = *(const float2*)((const float*)encg + (size_t)tv * 2048 + qq * 512 + h0 + hh);
        ex[qq] = e.x; ey[qq] = e.y;
      }
    }

    // ---- wait: all 16 producer blocks of this group must have published s.
    // One 64B line; lane tid polls dword tid -> one coalesced request/iter.
    if (s > 0 && tid < 16) {
      const int* sp = gslots + tid;
      while (ld4_cc_wait(sp) < s) {}
    }
    __syncthreads();                                     // bar A

    // ---- acquire: drop this XCD's (possibly stale) L2 lines, then read
    // ht through L2 so co-XCD siblings dedup the broadcast.
    l2_inv();
    __builtin_amdgcn_sched_barrier(0);

    const size_t rdo = (size_t)(s & 1) * (B_ * H_);
    const size_t wro = (size_t)((s & 1) ^ 1) * (B_ * H_);
    const ushort* hrow = ht_hi + rdo + (size_t)bg * 512;
    const ushort* lrow = ht_lo + rdo + (size_t)bg * 512;

    // ---- issue ALL staging loads (contiguous 256B/row per instruction);
    // vmcnt(4) drains h0 only.
    uintx4 a0, a1, b0_, b1_;            // h0: hi j0,j1 + lo j0,j1
    uintx4 a2, a3, b2_, b3_;            // h1: hi j2,j3 + lo j2,j3
    ld16_l2(hrow + sc8,       a0);
    ld16_l2(hrow + sc8 + 128, a1);
    ld16_l2(lrow + sc8,       b0_);
    ld16_l2(lrow + sc8 + 128, b1_);
    ld16_l2(hrow + sc8 + 256, a2);
    ld16_l2(hrow + sc8 + 384, a3);
    ld16_l2(lrow + sc8 + 256, b2_);
    ld16_l2(lrow + sc8 + 384, b3_);
    vm_wait4();                          // oldest 4 (h0) complete
    __builtin_amdgcn_sched_barrier(0);
    {
      const int base = sr * 512;
      *(uintx4*)(Ah_lds + base + (sc8 ^ swzw))         = a0;
      *(uintx4*)(Ah_lds + base + ((sc8 + 128) ^ swzw)) = a1;
      *(uintx4*)(Al_lds + base + (sc8 ^ swzw))         = b0_;
      *(uintx4*)(Al_lds + base + ((sc8 + 128) ^ swzw)) = b1_;
    }
    __syncthreads();                                     // bar B (h0 staged)

    floatx16 acc;
    if (kh == 0) {
      acc = mfma_half(0);               // reads h0 half of LDS
      gp_write(acc);
      vm_wait0();                        // h1 long since arrived
      __builtin_amdgcn_sched_barrier(0);
      const int base = sr * 512;
      *(uintx4*)(Ah_lds + base + ((sc8 + 256) ^ swzw)) = a2;
      *(uintx4*)(Ah_lds + base + ((sc8 + 384) ^ swzw)) = a3;
      *(uintx4*)(Al_lds + base + ((sc8 + 256) ^ swzw)) = b2_;
      *(uintx4*)(Al_lds + base + ((sc8 + 384) ^ swzw)) = b3_;
    } else {
      vm_wait0();
      __builtin_amdgcn_sched_barrier(0);
      const int base = sr * 512;
      *(uintx4*)(Ah_lds + base + ((sc8 + 256) ^ swzw)) = a2;
      *(uintx4*)(Ah_lds + base + ((sc8 + 384) ^ swzw)) = a3;
      *(uintx4*)(Al_lds + base + ((sc8 + 256) ^ swzw)) = b2_;
      *(uintx4*)(Al_lds + base + ((sc8 + 384) ^ swzw)) = b3_;
    }
    __syncthreads();                                     // bar C (h1 staged)

    if (kh == 1) {
      acc = mfma_half(256);             // reads h1 half of LDS
      gp_write(acc);
    }
    __syncthreads();                                     // bar D (gp complete)

    // ---- nonlinearity: thread owns (row sr, h-units hh, hh+1) ----
    {
      ev = fminf(fmaxf(ev, 0.f), 1.f);
      float Gv[4][2];
#pragma unroll
      for (int qq = 0; qq < 4; ++qq) {
        const int cb0 = (qq * 32 + hh) * 33 + sr;
        const int cb1 = (qq * 32 + hh + 1) * 33 + sr;
        Gv[qq][0] = clamp30(gp_lds[cb0] + gp_lds[4224 + cb0] + ex[qq] + bs[qq][0]);
        Gv[qq][1] = clamp30(gp_lds[cb1] + gp_lds[4224 + cb1] + ey[qq] + bs[qq][1]);
      }
      const float scale = 1.f + ev;
      float c0v = ct0 * scale;
      c0v = sigmoidf_(Gv[1][0]) * c0v + sigmoidf_(Gv[0][0]) * tanhf_(Gv[2][0]);
      const float h0v = sigmoidf_(Gv[3][0]) * tanhf_(c0v);
      ct0 = c0v;                                   // UNCLAMPED (ref semantics)
      float c1v = ct1 * scale;
      c1v = sigmoidf_(Gv[1][1]) * c1v + sigmoidf_(Gv[0][1]) * tanhf_(Gv[2][1]);
      const float h1v = sigmoidf_(Gv[3][1]) * tanhf_(c1v);
      ct1 = c1v;
      const ushort h0h = f2bfbits(h0v), h1h = f2bfbits(h1v);
      const ushort h0l = f2bfbits(h0v - bf2f_(h0h)), h1l = f2bfbits(h1v - bf2f_(h1h));
      const size_t wo = wro + (size_t)bg * 512 + h0 + hh;
      __hip_atomic_store((uint*)(ht_hi + wo), (uint)h0h | ((uint)h1h << 16),
                         __ATOMIC_RELAXED, __HIP_MEMORY_SCOPE_AGENT);
      __hip_atomic_store((uint*)(ht_lo + wo), (uint)h0l | ((uint)h1l << 16),
                         __ATOMIC_RELAXED, __HIP_MEMORY_SCOPE_AGENT);
    }

    // ---- per-block publish: every wave drains its ht stores to the
    // coherence point (vmcnt0), barrier proves ALL waves drained, then one
    // tid0 store flips the group-visible slot to s+1.
    vm_wait0();
    __syncthreads();                                     // bar E (all drained)
    if (tid == 0)
      __hip_atomic_store(myslot, s + 1, __ATOMIC_RELAXED, __HIP_MEMORY_SCOPE_AGENT);
  }
}

// ---------------------------------------------------------------------------
// K4: out[b] = sigmoid( (ht_hi+ht_lo)[b] . dec_W[tgt[b]] + dec_b[tgt[b]] )
// grid 128 x 256 (one wave per batch row). Final ht is in buffer parity 0.
// ---------------------------------------------------------------------------
__global__ void dec_kernel(const ushort* __restrict__ hthi, const ushort* __restrict__ htlo,
                           const float* __restrict__ decW, const float* __restrict__ decb,
                           const int* __restrict__ tgt, float* __restrict__ out) {
  const int w = threadIdx.x >> 6, l = threadIdx.x & 63;
  const int b = blockIdx.x * 4 + w;
  const int t = tgt[b];
  const uint4 hv = *(const uint4*)(hthi + (size_t)b * 512 + l * 8);
  const uint4 lv = *(const uint4*)(htlo + (size_t)b * 512 + l * 8);
  const float4 w0 = *(const float4*)(decW + (size_t)t * 512 + l * 8);
  const float4 w1 = *(const float4*)(decW + (size_t)t * 512 + l * 8 + 4);
  const uint ha[4] = {hv.x, hv.y, hv.z, hv.w};
  const uint la[4] = {lv.x, lv.y, lv.z, lv.w};
  float hf[8];
#pragma unroll
  for (int i = 0; i < 4; ++i) {
    hf[2*i]   = bf2f_((ushort)(ha[i] & 0xffffu)) + bf2f_((ushort)(la[i] & 0xffffu));
    hf[2*i+1] = bf2f_((ushort)(ha[i] >> 16))     + bf2f_((ushort)(la[i] >> 16));
  }
  float dot = hf[0]*w0.x + hf[1]*w0.y + hf[2]*w0.z + hf[3]*w0.w
            + hf[4]*w1.x + hf[5]*w1.y + hf[6]*w1.z + hf[7]*w1.w;
#pragma unroll
  for (int off = 32; off > 0; off >>= 1) dot += __shfl_xor(dot, off);
  if (l == 0) out[b] = sigmoidf_(dot + decb[t]);
}

extern "C" void kernel_launch(void* const* d_in, const int* in_sizes, int n_in,
                              void* d_out, int out_size, void* d_ws, size_t ws_size,
                              hipStream_t stream) {
  (void)in_sizes; (void)n_in; (void)out_size;
  const int* main_input = (const int*)d_in[0];
  const int* target_id  = (const int*)d_in[1];
  const int* user_seq   = (const int*)d_in[2];
  const int* skill_seq  = (const int*)d_in[3];
  const float* enc_emb  = (const float*)d_in[4];
  const float* P        = (const float*)d_in[5];
  const float* Q        = (const float*)d_in[6];
  const float* Pb       = (const float*)d_in[7];
  const float* Qb       = (const float*)d_in[8];
  const float* W_ih     = (const float*)d_in[9];
  const float* W_hh     = (const float*)d_in[10];
  const float* b_ih     = (const float*)d_in[11];
  const float* b_hh     = (const float*)d_in[12];
  const float* dec_W    = (const float*)d_in[13];
  const float* dec_b    = (const float*)d_in[14];
  float* out = (float*)d_out;

  // workspace layout (unchanged):
  //   [0)          ht_hi  2*512*512 bf16 = 1,048,576
  //   [1,048,576)  ht_lo  1,048,576                  -> 2,097,152
  //   [2,097,152)  ctr    256 ints used (16 lines)   -> 2,113,536 (region)
  //   [2,113,536)  etb    200*512 f32 = 409,600      -> 2,523,136
  //   [2,523,136)  encg   f32 16,400,384 (else bf16 8,200,192)
  char* wsb = (char*)d_ws;
  ushort* ht_hi = (ushort*)wsb;
  ushort* ht_lo = (ushort*)(wsb + 1048576);
  int* ctr = (int*)(wsb + 2097152);
  float* etb = (float*)(wsb + 2113536);
  char* encb = wsb + 2523136;
  const bool enc32 = ws_size >= (size_t)2523136 + 16400384;

  hipMemsetAsync(wsb, 0, 2113536, stream);   // ht(0)=0, all slots=0

  if (enc32)
    encg_kernel<float><<<dim3(32, 126), dim3(256), 0, stream>>>(enc_emb, W_ih, (float*)encb);
  else
    encg_kernel<ushort><<<dim3(32, 126), dim3(256), 0, stream>>>(enc_emb, W_ih, (ushort*)encb);
  mf_kernel<<<dim3(200, 128), dim3(256), 0, stream>>>(user_seq, skill_seq, P, Q, Pb, Qb, etb);
  if (enc32)
    lstm_kernel<float><<<dim3(256), dim3(512), 0, stream>>>(
        main_input, (const float*)encb, etb, W_hh, b_ih, b_hh, ht_hi, ht_lo, ctr);
  else
    lstm_kernel<ushort><<<dim3(256), dim3(512), 0, stream>>>(
        main_input, (const ushort*)encb, etb, W_hh, b_ih, b_hh, ht_hi, ht_lo, ctr);
  dec_kernel<<<dim3(128), dim3(256), 0, stream>>>(ht_hi, ht_lo, dec_W, dec_b, target_id, out);
}

// Round 8
// 2849.291 us; speedup vs baseline: 1.8704x; 1.8704x over previous
//
#include <hip/hip_runtime.h>

typedef __attribute__((ext_vector_type(8))) short short8;
typedef __attribute__((ext_vector_type(4))) float floatx4;
typedef __attribute__((ext_vector_type(16))) float floatx16;
typedef unsigned int uint;
typedef unsigned short ushort;
typedef unsigned long long ull;
typedef __attribute__((ext_vector_type(4))) uint uintx4;

#define B_ 512
#define S_ 200
#define H_ 512
#define VOCAB_ 2002

__device__ __forceinline__ ushort f2bfbits(float f) {
  union { float f; uint u; } c; c.f = f;
  uint u = c.u;
  u += 0x7fffu + ((u >> 16) & 1u);   // RNE
  return (ushort)(u >> 16);
}
__device__ __forceinline__ float bf2f_(ushort u) {
  union { uint i; float f; } c; c.i = ((uint)u) << 16; return c.f;
}
__device__ __forceinline__ float sigmoidf_(float x) { return 1.f / (1.f + __expf(-x)); }
__device__ __forceinline__ float tanhf_(float x) { return 2.f / (1.f + __expf(-2.f * x)) - 1.f; }
__device__ __forceinline__ float clamp30(float x) { return fminf(fmaxf(x, -30.f), 30.f); }

// split f32[8] -> (hi, lo) bf16 short8 pair; hi+lo carries ~16 mantissa bits
__device__ __forceinline__ void split8(const float* p, short8& hi, short8& lo) {
#pragma unroll
  for (int j = 0; j < 8; ++j) {
    const float f = p[j];
    const ushort h = f2bfbits(f);
    hi[j] = (short)h;
    lo[j] = (short)f2bfbits(f - bf2f_(h));
  }
}

// --- coherent (agent-safe, cache-bypassing) 16B load: issue only, no wait ---
__device__ __forceinline__ void ld16_cc(const void* p, uintx4& a) {
  asm volatile("global_load_dwordx4 %0, %1, off sc0 sc1"
               : "=&v"(a)
               : "v"(p));
}
// --- coherent 4B load with embedded drain (spin poll) ---
__device__ __forceinline__ int ld4_cc_wait(const int* p) {
  int v;
  asm volatile("global_load_dword %0, %1, off sc0 sc1\n\t"
               "s_waitcnt vmcnt(0)"
               : "=v"(v)
               : "v"(p)
               : "memory");
  return v;
}
__device__ __forceinline__ void vm_wait0() {
  asm volatile("s_waitcnt vmcnt(0)" ::: "memory");
}

// ---------------------------------------------------------------------------
// K1: EncGates[v][n] = emb[v]·W_ih[n]  (f32-accurate via 3-product split MFMA)
// ---------------------------------------------------------------------------
template <typename ET>
__global__ void encg_kernel(const float* __restrict__ emb, const float* __restrict__ Wih,
                            ET* __restrict__ encg) {
  const int w = threadIdx.x >> 6, l = threadIdx.x & 63;
  const int ln = l & 15, lk = l >> 4;
  const int n = (blockIdx.x * 4 + w) * 16 + ln;
  const int m = blockIdx.y * 16 + ln;
  const int mA = (m < VOCAB_) ? m : 0;
  const float* ap = emb + (size_t)mA * 512 + lk * 8;
  const float* bp = Wih + (size_t)n * 512 + lk * 8;
  floatx4 acc = {0.f, 0.f, 0.f, 0.f};
#pragma unroll 4
  for (int kk = 0; kk < 16; ++kk) {
    short8 ah, al, bh, bl;
    split8(ap + kk * 32, ah, al);
    split8(bp + kk * 32, bh, bl);
    acc = __builtin_amdgcn_mfma_f32_16x16x32_bf16(ah, bh, acc, 0, 0, 0);
    acc = __builtin_amdgcn_mfma_f32_16x16x32_bf16(ah, bl, acc, 0, 0, 0);
    acc = __builtin_amdgcn_mfma_f32_16x16x32_bf16(al, bh, acc, 0, 0, 0);
  }
#pragma unroll
  for (int r = 0; r < 4; ++r) {
    const int mo = blockIdx.y * 16 + lk * 4 + r;   // C/D: row=(lane>>4)*4+reg
    if (mo < VOCAB_) {
      if constexpr (sizeof(ET) == 2)
        encg[(size_t)mo * 2048 + n] = (ET)f2bfbits(acc[r]);
      else
        encg[(size_t)mo * 2048 + n] = acc[r];       // col = lane&15
    }
  }
}

// ---------------------------------------------------------------------------
// K2: et[s][b] = sigmoid(P[u].Q[k] + Pb[u] + Qb[k]); f32. grid (200,128)x256.
// ---------------------------------------------------------------------------
__global__ void mf_kernel(const int* __restrict__ us, const int* __restrict__ ss,
                          const float* __restrict__ P, const float* __restrict__ Q,
                          const float* __restrict__ Pb, const float* __restrict__ Qb,
                          float* __restrict__ etb) {
  const int s = blockIdx.x;
  const int w = threadIdx.x >> 6, l = threadIdx.x & 63;
  const int b = blockIdx.y * 4 + w;
  const int u = us[b * S_ + s];
  const int k = ss[b * S_ + s];
  const float4 p0 = *(const float4*)(P + (size_t)u * 512 + l * 8);
  const float4 p1 = *(const float4*)(P + (size_t)u * 512 + l * 8 + 4);
  const float4 q0 = *(const float4*)(Q + (size_t)k * 512 + l * 8);
  const float4 q1 = *(const float4*)(Q + (size_t)k * 512 + l * 8 + 4);
  float dot = p0.x*q0.x + p0.y*q0.y + p0.z*q0.z + p0.w*q0.w
            + p1.x*q1.x + p1.y*q1.y + p1.z*q1.z + p1.w*q1.w;
#pragma unroll
  for (int off = 32; off > 0; off >>= 1) dot += __shfl_xor(dot, off);
  if (l == 0)
    etb[s * B_ + b] = sigmoidf_(dot + Pb[u] + Qb[k]);
}

// ---------------------------------------------------------------------------
// K3: recurrent LSTM, f32-accurate. 256 blocks x 512 thr, 1 block/CU.
// group g=bid&15 owns 32 batch rows; slice ns=bid>>4 owns 32 h-units.
//
// r16 = r14 compute/numerics/fabric with a SPLIT-HALF concurrent schedule:
//  - The K-split is producer-aligned: h0 (cols 0..255) depends only on
//    producers ns=0..7; h1 on ns=8..15. kh0 waves (w<4) poll 0..7, fetch
//    + stage h0, MFMA h0; kh1 waves poll 8..15, fetch + stage h1, MFMA h1
//    -- two CONCURRENT chains (disjoint LDS col ranges + gp regions),
//    instead of r14's serialized poll-all -> fetch-h0 -> fetch-h1 chain.
//  - Intra-half sync: LDS release/acquire counter (4 adds per half per
//    step, monotone target 4(s+1)); block-wide barriers only at barD (gp
//    ready for nonlin) and barE (publish drain). Every spin is on a
//    monotone value with an unconditional producer -> no deadlock path.
//  - Staging: each half staged by its own 256 threads (srs=(tid&255)>>3,
//    cs=tid&7): 8x16B loads/thread, per-instruction row footprint 128B
//    contiguous; LDS image identical to r14 (same XOR swizzle granule).
//  - Poll/stage/store remain on the proven sc0 sc1 MALL fabric; no new
//    coherence assumptions (r7's buffer_inv and r4/5's sc0-only dropped).
// ---------------------------------------------------------------------------
template <typename ET>
__global__ __launch_bounds__(512, 2) void lstm_kernel(
    const int* __restrict__ tok, const ET* __restrict__ encg,
    const float* __restrict__ etb, const float* __restrict__ Whh,
    const float* __restrict__ bih, const float* __restrict__ bhh,
    ushort* ht_hi, ushort* ht_lo, int* ctr) {
  __shared__ __align__(16) ushort Ah_lds[32 * 512];   // 32,768 B (XOR-swizzled)
  __shared__ __align__(16) ushort Al_lds[32 * 512];   // 32,768 B
  __shared__ float gp_lds[2 * 128 * 33];              // 33,792 B
  __shared__ int cnt[2];                              // per-half stage counters

  const int bid = blockIdx.x;
  const int g = bid & 15, ns = bid >> 4;
  const int b0 = g * 32, h0 = ns * 32;
  const int tid = threadIdx.x;
  const int w = tid >> 6, l = tid & 63;
  const int nt = w & 3;                 // gate tile (i,f,g,o)
  const int kh = w >> 2;                // K-half (0: cols 0..255, 1: 256..511)

  // slots: group g's 16 producer blocks publish at ctr[g*16 + ns] -- one
  // 64-B line per group, one dword per block.
  int* const myslot = ctr + g * 16 + ns;
  const int* const gslots = ctr + g * 16;

  // --- preload + split this wave's W_hh rows (32 gate cols, its K-half) ---
  // B operand 32x32x16: lane l holds col=l&31, k=(l>>5)*8+j.
  short8 Bh[16], Bl[16];
  {
    const float* wr = Whh + (size_t)(nt * 512 + h0 + (l & 31)) * 512
                    + kh * 256 + (l >> 5) * 8;
#pragma unroll 4
    for (int kk = 0; kk < 16; ++kk)
      split8(wr + kk * 16, Bh[kk], Bl[kk]);
  }

  // nonlinearity-cell mapping (unchanged from r14)
  const int sr = tid >> 4;              // batch row (0..31)
  const int sc = tid & 15;
  const int hh = sc * 2;
  const int bg = b0 + sr;
  float ct0 = 0.f, ct1 = 0.f;

  float bs[4][2];
#pragma unroll
  for (int qq = 0; qq < 4; ++qq) {
    const int col = qq * 512 + h0 + hh;
    bs[qq][0] = bih[col] + bhh[col];
    bs[qq][1] = bih[col + 1] + bhh[col + 1];
  }

  // staging mapping: this thread stages its half's rows/cols
  const int srs = (tid & 255) >> 3;     // staged row 0..31
  const int cs = tid & 7;               // col-lane within the half
  const int colb = kh * 256 + cs * 8;   // ushort col base (+ j*64, j=0..3)
  const int bgs = b0 + srs;
  const int swzw = (srs & 7) << 3;      // writer swizzle (by staged row)
  const int swzr = (l & 7) << 3;        // reader swizzle (row = l&31)
  const int k8 = (l >> 5) * 8;          // lane k-offset within 16-wide step

  if (tid == 0) { cnt[0] = 0; cnt[1] = 0; }
  __syncthreads();

  // 48 MFMAs over one K-half; A row = l&31 from swizzled LDS.
  auto mfma_half = [&](int base) -> floatx16 {
    floatx16 a = {0.f,0.f,0.f,0.f,0.f,0.f,0.f,0.f,
                  0.f,0.f,0.f,0.f,0.f,0.f,0.f,0.f};
#pragma unroll
    for (int kk = 0; kk < 16; ++kk) {
      const int ao = (l & 31) * 512 + ((base + kk * 16 + k8) ^ swzr);
      const short8 ah = *(const short8*)(Ah_lds + ao);
      const short8 al = *(const short8*)(Al_lds + ao);
      a = __builtin_amdgcn_mfma_f32_32x32x16_bf16(ah, Bh[kk], a, 0, 0, 0);
      a = __builtin_amdgcn_mfma_f32_32x32x16_bf16(ah, Bl[kk], a, 0, 0, 0);
      a = __builtin_amdgcn_mfma_f32_32x32x16_bf16(al, Bh[kk], a, 0, 0, 0);
    }
    return a;
  };
  // C/D 32x32: col = lane&31, row = (reg&3) + 8*(reg>>2) + 4*(lane>>5)
  auto gp_write = [&](const floatx16& a) {
    float* gpw = gp_lds + kh * 4224 + (nt * 32 + (l & 31)) * 33 + 4 * (l >> 5);
#pragma unroll
    for (int r = 0; r < 16; ++r)
      gpw[(r & 3) + 8 * (r >> 2)] = a[r];
  };

  for (int s = 0; s < S_; ++s) {
    // ---- prefetch nonlinearity inputs (ht-independent; hides under poll) ----
    const int tv = tok[bg * S_ + s];
    float ev = etb[s * B_ + bg];
    float ex[4], ey[4];
#pragma unroll
    for (int qq = 0; qq < 4; ++qq) {
      if constexpr (sizeof(ET) == 2) {
        const uint e2 = *(const uint*)((const ushort*)encg + (size_t)tv * 2048 + qq * 512 + h0 + hh);
        ex[qq] = bf2f_((ushort)(e2 & 0xffffu)); ey[qq] = bf2f_((ushort)(e2 >> 16));
      } else {
        const float2 e = *(const float2*)((const float*)encg + (size_t)tv * 2048 + qq * 512 + h0 + hh);
        ex[qq] = e.x; ey[qq] = e.y;
      }
    }

    // ---- each wave polls ONLY its half's 8 producers (lanes 0..7) ----
    if (s > 0 && l < 8) {
      const int* sp = gslots + kh * 8 + l;
      while (ld4_cc_wait(sp) < s) {}
    }
    // wave reconverged: its half's producers have published step s.

    const size_t rdo = (size_t)(s & 1) * (B_ * H_);
    const size_t wro = (size_t)((s & 1) ^ 1) * (B_ * H_);

    // ---- stage own half: 4+4 x 16B loads, contiguous 128B/row/instr ----
    {
      const ushort* hrow = ht_hi + rdo + (size_t)bgs * 512;
      const ushort* lrow = ht_lo + rdo + (size_t)bgs * 512;
      uintx4 a0, a1, a2, a3, c0, c1, c2, c3;
      ld16_cc(hrow + colb,       a0);
      ld16_cc(hrow + colb + 64,  a1);
      ld16_cc(hrow + colb + 128, a2);
      ld16_cc(hrow + colb + 192, a3);
      ld16_cc(lrow + colb,       c0);
      ld16_cc(lrow + colb + 64,  c1);
      ld16_cc(lrow + colb + 128, c2);
      ld16_cc(lrow + colb + 192, c3);
      vm_wait0();
      __builtin_amdgcn_sched_barrier(0);
      const int base = srs * 512;
      *(uintx4*)(Ah_lds + base + ((colb)       ^ swzw)) = a0;
      *(uintx4*)(Ah_lds + base + ((colb + 64)  ^ swzw)) = a1;
      *(uintx4*)(Ah_lds + base + ((colb + 128) ^ swzw)) = a2;
      *(uintx4*)(Ah_lds + base + ((colb + 192) ^ swzw)) = a3;
      *(uintx4*)(Al_lds + base + ((colb)       ^ swzw)) = c0;
      *(uintx4*)(Al_lds + base + ((colb + 64)  ^ swzw)) = c1;
      *(uintx4*)(Al_lds + base + ((colb + 128) ^ swzw)) = c2;
      *(uintx4*)(Al_lds + base + ((colb + 192) ^ swzw)) = c3;
    }
    // ---- intra-half release/acquire: 4 waves per half ----
    if (l == 0)
      __hip_atomic_fetch_add(&cnt[kh], 1, __ATOMIC_RELEASE, __HIP_MEMORY_SCOPE_WORKGROUP);
    while (__hip_atomic_load(&cnt[kh], __ATOMIC_ACQUIRE, __HIP_MEMORY_SCOPE_WORKGROUP)
           < 4 * (s + 1)) {}
    __builtin_amdgcn_sched_barrier(0);

    // ---- MFMA own half, write gate partials ----
    floatx16 acc = mfma_half(kh * 256);
    gp_write(acc);
    __syncthreads();                                     // bar D (gp complete)

    // ---- nonlinearity: thread owns (row sr, h-units hh, hh+1) ----
    {
      ev = fminf(fmaxf(ev, 0.f), 1.f);
      float Gv[4][2];
#pragma unroll
      for (int qq = 0; qq < 4; ++qq) {
        const int cb0 = (qq * 32 + hh) * 33 + sr;
        const int cb1 = (qq * 32 + hh + 1) * 33 + sr;
        Gv[qq][0] = clamp30(gp_lds[cb0] + gp_lds[4224 + cb0] + ex[qq] + bs[qq][0]);
        Gv[qq][1] = clamp30(gp_lds[cb1] + gp_lds[4224 + cb1] + ey[qq] + bs[qq][1]);
      }
      const float scale = 1.f + ev;
      float c0v = ct0 * scale;
      c0v = sigmoidf_(Gv[1][0]) * c0v + sigmoidf_(Gv[0][0]) * tanhf_(Gv[2][0]);
      const float h0v = sigmoidf_(Gv[3][0]) * tanhf_(c0v);
      ct0 = c0v;                                   // UNCLAMPED (ref semantics)
      float c1v = ct1 * scale;
      c1v = sigmoidf_(Gv[1][1]) * c1v + sigmoidf_(Gv[0][1]) * tanhf_(Gv[2][1]);
      const float h1v = sigmoidf_(Gv[3][1]) * tanhf_(c1v);
      ct1 = c1v;
      const ushort h0h = f2bfbits(h0v), h1h = f2bfbits(h1v);
      const ushort h0l = f2bfbits(h0v - bf2f_(h0h)), h1l = f2bfbits(h1v - bf2f_(h1h));
      const size_t wo = wro + (size_t)bg * 512 + h0 + hh;
      __hip_atomic_store((uint*)(ht_hi + wo), (uint)h0h | ((uint)h1h << 16),
                         __ATOMIC_RELAXED, __HIP_MEMORY_SCOPE_AGENT);
      __hip_atomic_store((uint*)(ht_lo + wo), (uint)h0l | ((uint)h1l << 16),
                         __ATOMIC_RELAXED, __HIP_MEMORY_SCOPE_AGENT);
    }

    // ---- per-block publish: every wave drains its ht stores to the
    // coherence point (vmcnt0), barrier proves ALL waves drained, then one
    // tid0 store flips the group-visible slot to s+1.
    vm_wait0();
    __syncthreads();                                     // bar E (all drained)
    if (tid == 0)
      __hip_atomic_store(myslot, s + 1, __ATOMIC_RELAXED, __HIP_MEMORY_SCOPE_AGENT);
  }
}

// ---------------------------------------------------------------------------
// K4: out[b] = sigmoid( (ht_hi+ht_lo)[b] . dec_W[tgt[b]] + dec_b[tgt[b]] )
// grid 128 x 256 (one wave per batch row). Final ht is in buffer parity 0.
// ---------------------------------------------------------------------------
__global__ void dec_kernel(const ushort* __restrict__ hthi, const ushort* __restrict__ htlo,
                           const float* __restrict__ decW, const float* __restrict__ decb,
                           const int* __restrict__ tgt, float* __restrict__ out) {
  const int w = threadIdx.x >> 6, l = threadIdx.x & 63;
  const int b = blockIdx.x * 4 + w;
  const int t = tgt[b];
  const uint4 hv = *(const uint4*)(hthi + (size_t)b * 512 + l * 8);
  const uint4 lv = *(const uint4*)(htlo + (size_t)b * 512 + l * 8);
  const float4 w0 = *(const float4*)(decW + (size_t)t * 512 + l * 8);
  const float4 w1 = *(const float4*)(decW + (size_t)t * 512 + l * 8 + 4);
  const uint ha[4] = {hv.x, hv.y, hv.z, hv.w};
  const uint la[4] = {lv.x, lv.y, lv.z, lv.w};
  float hf[8];
#pragma unroll
  for (int i = 0; i < 4; ++i) {
    hf[2*i]   = bf2f_((ushort)(ha[i] & 0xffffu)) + bf2f_((ushort)(la[i] & 0xffffu));
    hf[2*i+1] = bf2f_((ushort)(ha[i] >> 16))     + bf2f_((ushort)(la[i] >> 16));
  }
  float dot = hf[0]*w0.x + hf[1]*w0.y + hf[2]*w0.z + hf[3]*w0.w
            + hf[4]*w1.x + hf[5]*w1.y + hf[6]*w1.z + hf[7]*w1.w;
#pragma unroll
  for (int off = 32; off > 0; off >>= 1) dot += __shfl_xor(dot, off);
  if (l == 0) out[b] = sigmoidf_(dot + decb[t]);
}

extern "C" void kernel_launch(void* const* d_in, const int* in_sizes, int n_in,
                              void* d_out, int out_size, void* d_ws, size_t ws_size,
                              hipStream_t stream) {
  (void)in_sizes; (void)n_in; (void)out_size;
  const int* main_input = (const int*)d_in[0];
  const int* target_id  = (const int*)d_in[1];
  const int* user_seq   = (const int*)d_in[2];
  const int* skill_seq  = (const int*)d_in[3];
  const float* enc_emb  = (const float*)d_in[4];
  const float* P        = (const float*)d_in[5];
  const float* Q        = (const float*)d_in[6];
  const float* Pb       = (const float*)d_in[7];
  const float* Qb       = (const float*)d_in[8];
  const float* W_ih     = (const float*)d_in[9];
  const float* W_hh     = (const float*)d_in[10];
  const float* b_ih     = (const float*)d_in[11];
  const float* b_hh     = (const float*)d_in[12];
  const float* dec_W    = (const float*)d_in[13];
  const float* dec_b    = (const float*)d_in[14];
  float* out = (float*)d_out;

  // workspace layout (unchanged):
  //   [0)          ht_hi  2*512*512 bf16 = 1,048,576
  //   [1,048,576)  ht_lo  1,048,576                  -> 2,097,152
  //   [2,097,152)  ctr    256 ints used (16 lines)   -> 2,113,536 (region)
  //   [2,113,536)  etb    200*512 f32 = 409,600      -> 2,523,136
  //   [2,523,136)  encg   f32 16,400,384 (else bf16 8,200,192)
  char* wsb = (char*)d_ws;
  ushort* ht_hi = (ushort*)wsb;
  ushort* ht_lo = (ushort*)(wsb + 1048576);
  int* ctr = (int*)(wsb + 2097152);
  float* etb = (float*)(wsb + 2113536);
  char* encb = wsb + 2523136;
  const bool enc32 = ws_size >= (size_t)2523136 + 16400384;

  hipMemsetAsync(wsb, 0, 2113536, stream);   // ht(0)=0, all slots=0

  if (enc32)
    encg_kernel<float><<<dim3(32, 126), dim3(256), 0, stream>>>(enc_emb, W_ih, (float*)encb);
  else
    encg_kernel<ushort><<<dim3(32, 126), dim3(256), 0, stream>>>(enc_emb, W_ih, (ushort*)encb);
  mf_kernel<<<dim3(200, 128), dim3(256), 0, stream>>>(user_seq, skill_seq, P, Q, Pb, Qb, etb);
  if (enc32)
    lstm_kernel<float><<<dim3(256), dim3(512), 0, stream>>>(
        main_input, (const float*)encb, etb, W_hh, b_ih, b_hh, ht_hi, ht_lo, ctr);
  else
    lstm_kernel<ushort><<<dim3(256), dim3(512), 0, stream>>>(
        main_input, (const ushort*)encb, etb, W_hh, b_ih, b_hh, ht_hi, ht_lo, ctr);
  dec_kernel<<<dim3(128), dim3(256), 0, stream>>>(ht_hi, ht_lo, dec_W, dec_b, target_id, out);
}

// Round 9
// 2665.032 us; speedup vs baseline: 1.9997x; 1.0691x over previous
//
#include <hip/hip_runtime.h>

typedef __attribute__((ext_vector_type(8))) short short8;
typedef __attribute__((ext_vector_type(4))) float floatx4;
typedef __attribute__((ext_vector_type(16))) float floatx16;
typedef unsigned int uint;
typedef unsigned short ushort;
typedef unsigned long long ull;
typedef __attribute__((ext_vector_type(4))) uint uintx4;

#define B_ 512
#define S_ 200
#define H_ 512
#define VOCAB_ 2002

__device__ __forceinline__ ushort f2bfbits(float f) {
  union { float f; uint u; } c; c.f = f;
  uint u = c.u;
  u += 0x7fffu + ((u >> 16) & 1u);   // RNE
  return (ushort)(u >> 16);
}
__device__ __forceinline__ float bf2f_(ushort u) {
  union { uint i; float f; } c; c.i = ((uint)u) << 16; return c.f;
}
__device__ __forceinline__ float sigmoidf_(float x) { return 1.f / (1.f + __expf(-x)); }
__device__ __forceinline__ float tanhf_(float x) { return 2.f / (1.f + __expf(-2.f * x)) - 1.f; }
__device__ __forceinline__ float clamp30(float x) { return fminf(fmaxf(x, -30.f), 30.f); }

// split f32[8] -> (hi, lo) bf16 short8 pair; hi+lo carries ~16 mantissa bits
__device__ __forceinline__ void split8(const float* p, short8& hi, short8& lo) {
#pragma unroll
  for (int j = 0; j < 8; ++j) {
    const float f = p[j];
    const ushort h = f2bfbits(f);
    hi[j] = (short)h;
    lo[j] = (short)f2bfbits(f - bf2f_(h));
  }
}

// --- coherent (agent-safe, cache-bypassing) 16B load: issue only, no wait ---
__device__ __forceinline__ void ld16_cc(const void* p, uintx4& a) {
  asm volatile("global_load_dwordx4 %0, %1, off sc0 sc1"
               : "=&v"(a)
               : "v"(p));
}
// --- coherent 4B load with embedded drain (spin poll; 16 lanes = 1 line) ---
__device__ __forceinline__ int ld4_cc_wait(const int* p) {
  int v;
  asm volatile("global_load_dword %0, %1, off sc0 sc1\n\t"
               "s_waitcnt vmcnt(0)"
               : "=v"(v)
               : "v"(p)
               : "memory");
  return v;
}
__device__ __forceinline__ void vm_wait0() {
  asm volatile("s_waitcnt vmcnt(0)" ::: "memory");
}
__device__ __forceinline__ void vm_wait4() {
  asm volatile("s_waitcnt vmcnt(4)" ::: "memory");
}

// ---------------------------------------------------------------------------
// K1: EncGates[v][n] = emb[v]·W_ih[n]  (f32-accurate via 3-product split MFMA)
// grid (32,126) x 256 thr (4 waves, one 16x16 tile each). Biases added later.
// ---------------------------------------------------------------------------
template <typename ET>
__global__ void encg_kernel(const float* __restrict__ emb, const float* __restrict__ Wih,
                            ET* __restrict__ encg) {
  const int w = threadIdx.x >> 6, l = threadIdx.x & 63;
  const int ln = l & 15, lk = l >> 4;
  const int n = (blockIdx.x * 4 + w) * 16 + ln;
  const int m = blockIdx.y * 16 + ln;
  const int mA = (m < VOCAB_) ? m : 0;
  const float* ap = emb + (size_t)mA * 512 + lk * 8;
  const float* bp = Wih + (size_t)n * 512 + lk * 8;
  floatx4 acc = {0.f, 0.f, 0.f, 0.f};
#pragma unroll 4
  for (int kk = 0; kk < 16; ++kk) {
    short8 ah, al, bh, bl;
    split8(ap + kk * 32, ah, al);
    split8(bp + kk * 32, bh, bl);
    acc = __builtin_amdgcn_mfma_f32_16x16x32_bf16(ah, bh, acc, 0, 0, 0);
    acc = __builtin_amdgcn_mfma_f32_16x16x32_bf16(ah, bl, acc, 0, 0, 0);
    acc = __builtin_amdgcn_mfma_f32_16x16x32_bf16(al, bh, acc, 0, 0, 0);
  }
#pragma unroll
  for (int r = 0; r < 4; ++r) {
    const int mo = blockIdx.y * 16 + lk * 4 + r;   // C/D: row=(lane>>4)*4+reg
    if (mo < VOCAB_) {
      if constexpr (sizeof(ET) == 2)
        encg[(size_t)mo * 2048 + n] = (ET)f2bfbits(acc[r]);
      else
        encg[(size_t)mo * 2048 + n] = acc[r];       // col = lane&15
    }
  }
}

// ---------------------------------------------------------------------------
// K2: et[s][b] = sigmoid(P[u].Q[k] + Pb[u] + Qb[k]); f32. grid (200,128)x256.
// ---------------------------------------------------------------------------
__global__ void mf_kernel(const int* __restrict__ us, const int* __restrict__ ss,
                          const float* __restrict__ P, const float* __restrict__ Q,
                          const float* __restrict__ Pb, const float* __restrict__ Qb,
                          float* __restrict__ etb) {
  const int s = blockIdx.x;
  const int w = threadIdx.x >> 6, l = threadIdx.x & 63;
  const int b = blockIdx.y * 4 + w;
  const int u = us[b * S_ + s];
  const int k = ss[b * S_ + s];
  const float4 p0 = *(const float4*)(P + (size_t)u * 512 + l * 8);
  const float4 p1 = *(const float4*)(P + (size_t)u * 512 + l * 8 + 4);
  const float4 q0 = *(const float4*)(Q + (size_t)k * 512 + l * 8);
  const float4 q1 = *(const float4*)(Q + (size_t)k * 512 + l * 8 + 4);
  float dot = p0.x*q0.x + p0.y*q0.y + p0.z*q0.z + p0.w*q0.w
            + p1.x*q1.x + p1.y*q1.y + p1.z*q1.z + p1.w*q1.w;
#pragma unroll
  for (int off = 32; off > 0; off >>= 1) dot += __shfl_xor(dot, off);
  if (l == 0)
    etb[s * B_ + b] = sigmoidf_(dot + Pb[u] + Qb[k]);
}

// ---------------------------------------------------------------------------
// K3: recurrent LSTM, f32-accurate. 256 blocks x 512 thr, 1 block/CU.
// group g=bid&15 owns 32 batch rows; slice ns=bid>>4 owns 32 h-units.
//
// r17 = EXACT REVERT to r14/r6 (best measured: total 2672.9us, lstm ~2538).
// Closed-out experiments, all measured on this problem:
//  - swizzle+pipeline (r1: -8%), 32x32 MFMA K-half split (r2: null),
//    poll-footprint 16x shrink (r3: null), XCD sc0-only exchange (r4/r5:
//    container crash x2), contiguous staging remap (r6: FETCH-null),
//    buffer_inv L2 dedup (r7: 2x regression), split-half concurrent
//    chains (r8: null-to-negative).
//  - Conclusion: duration = FETCH / ~2.85 TB/s in every variant; FETCH is
//    structurally floored (16x register-forced ht broadcast x HW request
//    tax + gathers); the MALL exchange path is bandwidth-saturated.
// ---------------------------------------------------------------------------
template <typename ET>
__global__ __launch_bounds__(512, 2) void lstm_kernel(
    const int* __restrict__ tok, const ET* __restrict__ encg,
    const float* __restrict__ etb, const float* __restrict__ Whh,
    const float* __restrict__ bih, const float* __restrict__ bhh,
    ushort* ht_hi, ushort* ht_lo, int* ctr) {
  __shared__ __align__(16) ushort Ah_lds[32 * 512];   // 32,768 B (XOR-swizzled)
  __shared__ __align__(16) ushort Al_lds[32 * 512];   // 32,768 B
  __shared__ float gp_lds[2 * 128 * 33];              // 33,792 B

  const int bid = blockIdx.x;
  const int g = bid & 15, ns = bid >> 4;
  const int b0 = g * 32, h0 = ns * 32;
  const int tid = threadIdx.x;
  const int w = tid >> 6, l = tid & 63;
  const int nt = w & 3;                 // gate tile (i,f,g,o)
  const int kh = w >> 2;                // K-half (0: cols 0..255, 1: 256..511)

  // slots: group g's 16 producer blocks publish at ctr[g*16 + ns] -- one
  // 64-B line per group, one dword per block.
  int* const myslot = ctr + g * 16 + ns;
  const int* const gslots = ctr + g * 16;

  // --- preload + split this wave's W_hh rows (32 gate cols, its K-half) ---
  // B operand 32x32x16: lane l holds col=l&31, k=(l>>5)*8+j.
  short8 Bh[16], Bl[16];
  {
    const float* wr = Whh + (size_t)(nt * 512 + h0 + (l & 31)) * 512
                    + kh * 256 + (l >> 5) * 8;
#pragma unroll 4
    for (int kk = 0; kk < 16; ++kk)
      split8(wr + kk * 16, Bh[kk], Bl[kk]);
  }

  const int sr = tid >> 4;              // batch row within group (0..31)
  const int sc = tid & 15;              // 16 stagers per row
  const int hh = sc * 2;
  const int bg = b0 + sr;
  float ct0 = 0.f, ct1 = 0.f;

  float bs[4][2];
#pragma unroll
  for (int qq = 0; qq < 4; ++qq) {
    const int col = qq * 512 + h0 + hh;
    bs[qq][0] = bih[col] + bhh[col];
    bs[qq][1] = bih[col + 1] + bhh[col + 1];
  }

  const int swzw = (sr & 7) << 3;       // writer swizzle (ushort units)
  const int swzr = (l & 7) << 3;        // reader swizzle (row = l&31 -> row&7 = l&7)
  const int k8 = (l >> 5) * 8;          // lane's k-offset within 16-wide step
  const int sc8 = sc * 8;               // this thread's base chunk col (ushorts)

  // 48 MFMAs over one K-half; A row = l&31 from swizzled LDS.
  auto mfma_half = [&](int base) -> floatx16 {
    floatx16 a = {0.f,0.f,0.f,0.f,0.f,0.f,0.f,0.f,
                  0.f,0.f,0.f,0.f,0.f,0.f,0.f,0.f};
#pragma unroll
    for (int kk = 0; kk < 16; ++kk) {
      const int ao = (l & 31) * 512 + ((base + kk * 16 + k8) ^ swzr);
      const short8 ah = *(const short8*)(Ah_lds + ao);
      const short8 al = *(const short8*)(Al_lds + ao);
      a = __builtin_amdgcn_mfma_f32_32x32x16_bf16(ah, Bh[kk], a, 0, 0, 0);
      a = __builtin_amdgcn_mfma_f32_32x32x16_bf16(ah, Bl[kk], a, 0, 0, 0);
      a = __builtin_amdgcn_mfma_f32_32x32x16_bf16(al, Bh[kk], a, 0, 0, 0);
    }
    return a;
  };
  // C/D 32x32: col = lane&31, row = (reg&3) + 8*(reg>>2) + 4*(lane>>5)
  auto gp_write = [&](const floatx16& a) {
    float* gpw = gp_lds + kh * 4224 + (nt * 32 + (l & 31)) * 33 + 4 * (l >> 5);
#pragma unroll
    for (int r = 0; r < 16; ++r)
      gpw[(r & 3) + 8 * (r >> 2)] = a[r];
  };

  for (int s = 0; s < S_; ++s) {
    // ---- prefetch nonlinearity inputs (ht-independent; hides under spin) ----
    const int tv = tok[bg * S_ + s];
    float ev = etb[s * B_ + bg];
    float ex[4], ey[4];
#pragma unroll
    for (int qq = 0; qq < 4; ++qq) {
      if constexpr (sizeof(ET) == 2) {
        const uint e2 = *(const uint*)((const ushort*)encg + (size_t)tv * 2048 + qq * 512 + h0 + hh);
        ex[qq] = bf2f_((ushort)(e2 & 0xffffu)); ey[qq] = bf2f_((ushort)(e2 >> 16));
      } else {
        const float2 e = *(const float2*)((const float*)encg + (size_t)tv * 2048 + qq * 512 + h0 + hh);
        ex[qq] = e.x; ey[qq] = e.y;
      }
    }

    // ---- wait: all 16 producer blocks of this group must have published s.
    // One 64B line; lane tid polls dword tid -> one coalesced request/iter.
    if (s > 0 && tid < 16) {
      const int* sp = gslots + tid;
      while (ld4_cc_wait(sp) < s) {}
    }
    __syncthreads();                                     // bar A

    const size_t rdo = (size_t)(s & 1) * (B_ * H_);
    const size_t wro = (size_t)((s & 1) ^ 1) * (B_ * H_);
    const ushort* hrow = ht_hi + rdo + (size_t)bg * 512;
    const ushort* lrow = ht_lo + rdo + (size_t)bg * 512;

    // ---- issue ALL staging loads (contiguous 256B/row per instruction);
    // vmcnt(4) drains h0 only.
    uintx4 a0, a1, b0_, b1_;            // h0: hi j0,j1 + lo j0,j1
    uintx4 a2, a3, b2_, b3_;            // h1: hi j2,j3 + lo j2,j3
    __builtin_amdgcn_sched_barrier(0);
    ld16_cc(hrow + sc8,       a0);
    ld16_cc(hrow + sc8 + 128, a1);
    ld16_cc(lrow + sc8,       b0_);
    ld16_cc(lrow + sc8 + 128, b1_);
    ld16_cc(hrow + sc8 + 256, a2);
    ld16_cc(hrow + sc8 + 384, a3);
    ld16_cc(lrow + sc8 + 256, b2_);
    ld16_cc(lrow + sc8 + 384, b3_);
    vm_wait4();                          // oldest 4 (h0) complete
    __builtin_amdgcn_sched_barrier(0);
    {
      const int base = sr * 512;
      *(uintx4*)(Ah_lds + base + (sc8 ^ swzw))         = a0;
      *(uintx4*)(Ah_lds + base + ((sc8 + 128) ^ swzw)) = a1;
      *(uintx4*)(Al_lds + base + (sc8 ^ swzw))         = b0_;
      *(uintx4*)(Al_lds + base + ((sc8 + 128) ^ swzw)) = b1_;
    }
    __syncthreads();                                     // bar B (h0 staged)

    floatx16 acc;
    if (kh == 0) {
      acc = mfma_half(0);               // reads h0 half of LDS
      gp_write(acc);
      vm_wait0();                        // h1 long since arrived
      __builtin_amdgcn_sched_barrier(0);
      const int base = sr * 512;
      *(uintx4*)(Ah_lds + base + ((sc8 + 256) ^ swzw)) = a2;
      *(uintx4*)(Ah_lds + base + ((sc8 + 384) ^ swzw)) = a3;
      *(uintx4*)(Al_lds + base + ((sc8 + 256) ^ swzw)) = b2_;
      *(uintx4*)(Al_lds + base + ((sc8 + 384) ^ swzw)) = b3_;
    } else {
      vm_wait0();
      __builtin_amdgcn_sched_barrier(0);
      const int base = sr * 512;
      *(uintx4*)(Ah_lds + base + ((sc8 + 256) ^ swzw)) = a2;
      *(uintx4*)(Ah_lds + base + ((sc8 + 384) ^ swzw)) = a3;
      *(uintx4*)(Al_lds + base + ((sc8 + 256) ^ swzw)) = b2_;
      *(uintx4*)(Al_lds + base + ((sc8 + 384) ^ swzw)) = b3_;
    }
    __syncthreads();                                     // bar C (h1 staged)

    if (kh == 1) {
      acc = mfma_half(256);             // reads h1 half of LDS
      gp_write(acc);
    }
    __syncthreads();                                     // bar D (gp complete)

    // ---- nonlinearity: thread owns (row sr, h-units hh, hh+1) ----
    {
      ev = fminf(fmaxf(ev, 0.f), 1.f);
      float Gv[4][2];
#pragma unroll
      for (int qq = 0; qq < 4; ++qq) {
        const int cb0 = (qq * 32 + hh) * 33 + sr;
        const int cb1 = (qq * 32 + hh + 1) * 33 + sr;
        Gv[qq][0] = clamp30(gp_lds[cb0] + gp_lds[4224 + cb0] + ex[qq] + bs[qq][0]);
        Gv[qq][1] = clamp30(gp_lds[cb1] + gp_lds[4224 + cb1] + ey[qq] + bs[qq][1]);
      }
      const float scale = 1.f + ev;
      float c0v = ct0 * scale;
      c0v = sigmoidf_(Gv[1][0]) * c0v + sigmoidf_(Gv[0][0]) * tanhf_(Gv[2][0]);
      const float h0v = sigmoidf_(Gv[3][0]) * tanhf_(c0v);
      ct0 = c0v;                                   // UNCLAMPED (ref semantics)
      float c1v = ct1 * scale;
      c1v = sigmoidf_(Gv[1][1]) * c1v + sigmoidf_(Gv[0][1]) * tanhf_(Gv[2][1]);
      const float h1v = sigmoidf_(Gv[3][1]) * tanhf_(c1v);
      ct1 = c1v;
      const ushort h0h = f2bfbits(h0v), h1h = f2bfbits(h1v);
      const ushort h0l = f2bfbits(h0v - bf2f_(h0h)), h1l = f2bfbits(h1v - bf2f_(h1h));
      const size_t wo = wro + (size_t)bg * 512 + h0 + hh;
      __hip_atomic_store((uint*)(ht_hi + wo), (uint)h0h | ((uint)h1h << 16),
                         __ATOMIC_RELAXED, __HIP_MEMORY_SCOPE_AGENT);
      __hip_atomic_store((uint*)(ht_lo + wo), (uint)h0l | ((uint)h1l << 16),
                         __ATOMIC_RELAXED, __HIP_MEMORY_SCOPE_AGENT);
    }

    // ---- per-block publish: every wave drains its ht stores to the
    // coherence point (vmcnt0), barrier proves ALL waves drained, then one
    // tid0 store flips the group-visible slot to s+1.
    vm_wait0();
    __syncthreads();                                     // bar E (all drained)
    if (tid == 0)
      __hip_atomic_store(myslot, s + 1, __ATOMIC_RELAXED, __HIP_MEMORY_SCOPE_AGENT);
  }
}

// ---------------------------------------------------------------------------
// K4: out[b] = sigmoid( (ht_hi+ht_lo)[b] . dec_W[tgt[b]] + dec_b[tgt[b]] )
// grid 128 x 256 (one wave per batch row). Final ht is in buffer parity 0.
// ---------------------------------------------------------------------------
__global__ void dec_kernel(const ushort* __restrict__ hthi, const ushort* __restrict__ htlo,
                           const float* __restrict__ decW, const float* __restrict__ decb,
                           const int* __restrict__ tgt, float* __restrict__ out) {
  const int w = threadIdx.x >> 6, l = threadIdx.x & 63;
  const int b = blockIdx.x * 4 + w;
  const int t = tgt[b];
  const uint4 hv = *(const uint4*)(hthi + (size_t)b * 512 + l * 8);
  const uint4 lv = *(const uint4*)(htlo + (size_t)b * 512 + l * 8);
  const float4 w0 = *(const float4*)(decW + (size_t)t * 512 + l * 8);
  const float4 w1 = *(const float4*)(decW + (size_t)t * 512 + l * 8 + 4);
  const uint ha[4] = {hv.x, hv.y, hv.z, hv.w};
  const uint la[4] = {lv.x, lv.y, lv.z, lv.w};
  float hf[8];
#pragma unroll
  for (int i = 0; i < 4; ++i) {
    hf[2*i]   = bf2f_((ushort)(ha[i] & 0xffffu)) + bf2f_((ushort)(la[i] & 0xffffu));
    hf[2*i+1] = bf2f_((ushort)(ha[i] >> 16))     + bf2f_((ushort)(la[i] >> 16));
  }
  float dot = hf[0]*w0.x + hf[1]*w0.y + hf[2]*w0.z + hf[3]*w0.w
            + hf[4]*w1.x + hf[5]*w1.y + hf[6]*w1.z + hf[7]*w1.w;
#pragma unroll
  for (int off = 32; off > 0; off >>= 1) dot += __shfl_xor(dot, off);
  if (l == 0) out[b] = sigmoidf_(dot + decb[t]);
}

extern "C" void kernel_launch(void* const* d_in, const int* in_sizes, int n_in,
                              void* d_out, int out_size, void* d_ws, size_t ws_size,
                              hipStream_t stream) {
  (void)in_sizes; (void)n_in; (void)out_size;
  const int* main_input = (const int*)d_in[0];
  const int* target_id  = (const int*)d_in[1];
  const int* user_seq   = (const int*)d_in[2];
  const int* skill_seq  = (const int*)d_in[3];
  const float* enc_emb  = (const float*)d_in[4];
  const float* P        = (const float*)d_in[5];
  const float* Q        = (const float*)d_in[6];
  const float* Pb       = (const float*)d_in[7];
  const float* Qb       = (const float*)d_in[8];
  const float* W_ih     = (const float*)d_in[9];
  const float* W_hh     = (const float*)d_in[10];
  const float* b_ih     = (const float*)d_in[11];
  const float* b_hh     = (const float*)d_in[12];
  const float* dec_W    = (const float*)d_in[13];
  const float* dec_b    = (const float*)d_in[14];
  float* out = (float*)d_out;

  // workspace layout (unchanged):
  //   [0)          ht_hi  2*512*512 bf16 = 1,048,576
  //   [1,048,576)  ht_lo  1,048,576                  -> 2,097,152
  //   [2,097,152)  ctr    256 ints used (16 lines)   -> 2,113,536 (region)
  //   [2,113,536)  etb    200*512 f32 = 409,600      -> 2,523,136
  //   [2,523,136)  encg   f32 16,400,384 (else bf16 8,200,192)
  char* wsb = (char*)d_ws;
  ushort* ht_hi = (ushort*)wsb;
  ushort* ht_lo = (ushort*)(wsb + 1048576);
  int* ctr = (int*)(wsb + 2097152);
  float* etb = (float*)(wsb + 2113536);
  char* encb = wsb + 2523136;
  const bool enc32 = ws_size >= (size_t)2523136 + 16400384;

  hipMemsetAsync(wsb, 0, 2113536, stream);   // ht(0)=0, all slots=0

  if (enc32)
    encg_kernel<float><<<dim3(32, 126), dim3(256), 0, stream>>>(enc_emb, W_ih, (float*)encb);
  else
    encg_kernel<ushort><<<dim3(32, 126), dim3(256), 0, stream>>>(enc_emb, W_ih, (ushort*)encb);
  mf_kernel<<<dim3(200, 128), dim3(256), 0, stream>>>(user_seq, skill_seq, P, Q, Pb, Qb, etb);
  if (enc32)
    lstm_kernel<float><<<dim3(256), dim3(512), 0, stream>>>(
        main_input, (const float*)encb, etb, W_hh, b_ih, b_hh, ht_hi, ht_lo, ctr);
  else
    lstm_kernel<ushort><<<dim3(256), dim3(512), 0, stream>>>(
        main_input, (const ushort*)encb, etb, W_hh, b_ih, b_hh, ht_hi, ht_lo, ctr);
  dec_kernel<<<dim3(128), dim3(256), 0, stream>>>(ht_hi, ht_lo, dec_W, dec_b, target_id, out);
}